// Round 8
// baseline (28.501 us; speedup 1.0000x reference)
//
#include <hip/hip_runtime.h>
#include <math.h>

// Problem constants (match reference)
constexpr int   BB    = 32;
constexpr int   NF    = 500;
constexpr int   FS    = 240;
constexpr int   TT    = NF * FS;     // 120000 samples per row
constexpr int   HH    = 8;
constexpr float ALPHA = 0.1f;

constexpr int SPT = 4;               // samples per thread (240 % 4 == 0)
constexpr int BLK = 256;
// 32 rows * 120000 / (256*4) = 3750 blocks, exact cover.

__device__ __forceinline__ float sin_rev(float fr) {
    // fr in [-0.5, 0.5] revolutions; v_sin_f32: D = sin(S0 * 2pi)
#if __has_builtin(__builtin_amdgcn_sinf)
    return __builtin_amdgcn_sinf(fr);
#else
    return __sinf(fr * 6.28318530717958647692f);
#endif
}

__device__ __forceinline__ float tanh_fast(float x) {
    // tanh(x) = 1 - 2/(e^{2x}+1); exp saturation gives correct +-1 limits.
    const float e = __expf(2.0f * x);
#if __has_builtin(__builtin_amdgcn_rcpf)
    const float r = __builtin_amdgcn_rcpf(e + 1.0f);
#else
    const float r = 1.0f / (e + 1.0f);
#endif
    return fmaf(-2.0f, r, 1.0f);
}

// ---------------------------------------------------------------------------
// Flat-grid fused kernel, harmonic-rotated loads:
//   - per block, harmonics are visited in order (hh + bid) & 7 so concurrent
//     blocks hit different 15.36MB-strided streams at any instant
//     (all stream bases are congruent mod 4KB -> same channel phase).
//   - all 8 float4 loads hoisted into registers (compile-time indexed)
//     before the dependent fma/sin chain.
// ---------------------------------------------------------------------------
__global__ __launch_bounds__(BLK) void synth_fused(const float* __restrict__ f0s,
                                                   const float* __restrict__ phi,
                                                   const float* __restrict__ amp,
                                                   const float* __restrict__ noise,
                                                   float* __restrict__ out) {
    const int bid  = blockIdx.x;
    const int tid  = threadIdx.x;
    const int lane = tid & 63;
    const int wv   = tid >> 6;

    const int s_first = bid * (BLK * SPT);              // first sample of block
    const int b0 = s_first / TT;
    const int b1 = (s_first + BLK * SPT - 1) / TT;      // row of last sample

    __shared__ float2 sfr[NF];          // row b0: {frac(prefix_rev), dphi_rev}
    __shared__ float2 sfr1[8];          // row b1: first frames (prefix starts at 0)
    __shared__ double wtot[BLK / 64];   // per-wave scan totals

    const float  TWO_PI_F = 6.28318530717958647692f;
    const double INV_2PI  = 0.15915494309189533576;

    // ---- cooperative frame-level phase prefix scan for row b0 ----
    {
        const int fi = 2 * tid;
        double d0 = 0.0, d1 = 0.0;
        if (fi < NF) {
            const float dphi = (TWO_PI_F * f0s[b0 * NF + fi]) / 24000.0f;  // f32, np op order
            d0 = (double)dphi * INV_2PI;
        }
        if (fi + 1 < NF) {
            const float dphi = (TWO_PI_F * f0s[b0 * NF + fi + 1]) / 24000.0f;
            d1 = (double)dphi * INV_2PI;
        }

        const double s = (d0 + d1) * 240.0;   // revolutions across this thread's 2 frames
        double run = s;
        for (int delta = 1; delta < 64; delta <<= 1) {
            const double o = __shfl_up(run, delta, 64);
            if (lane >= delta) run += o;
        }
        if (lane == 63) wtot[wv] = run;
        __syncthreads();

        double woff = 0.0;
        for (int w2 = 0; w2 < wv; ++w2) woff += wtot[w2];
        double pref = woff + (run - s);       // exclusive prefix at frame fi

        if (fi < NF) {
            const double fx0 = pref - rint(pref);
            sfr[fi] = make_float2((float)fx0, (float)d0);
            if (fi + 1 < NF) {
                const double p1  = pref + d0 * 240.0;
                const double fx1 = p1 - rint(p1);
                sfr[fi + 1] = make_float2((float)fx1, (float)d1);
            }
        }

        // boundary rows: first frames of b1 (cumsum restarts at 0 per row)
        if (b1 != b0 && tid == 0) {
            double acc = 0.0;
#pragma unroll
            for (int g = 0; g < 8; ++g) {
                const float dphi = (TWO_PI_F * f0s[b1 * NF + g]) / 24000.0f;
                const double dg  = (double)dphi * INV_2PI;
                const double fx  = acc - rint(acc);
                sfr1[g] = make_float2((float)fx, (float)dg);
                acc += dg * 240.0;
            }
        }
        __syncthreads();
    }

    // ---- per-thread synth of 4 consecutive samples ----
    const int s = s_first + tid * SPT;        // global flat sample index
    const int b = s / TT;
    const int t = s - b * TT;
    const int f = t / FS;
    const int j = t - f * FS;                 // multiple of 4, within one frame
    const size_t base = (size_t)s;            // == b*TT + t in flat layout

    const float2 fd = (b == b0) ? sfr[f] : sfr1[f];
    const float  dr = fd.y;
    const bool   voiced = (dr > 0.0f);

    float cs[SPT];
    cs[0] = fd.x + (float)(j + 1) * dr;       // inclusive cumsum semantics
#pragma unroll
    for (int e = 1; e < SPT; ++e) cs[e] = cs[e - 1] + dr;

    const float INV2PIf = 0.15915494309189533576f;
    const int   rot     = bid & 7;
    const size_t HSTRIDE = (size_t)BB * (size_t)TT;   // elements between harmonics

    // hoisted loads, rotated harmonic order (m indexed by compile-time hh)
    float4 m[HH];
#pragma unroll
    for (int hh = 0; hh < HH; ++hh) {
        const int h = (hh + rot) & 7;
        m[hh] = *reinterpret_cast<const float4*>(noise + (size_t)h * HSTRIDE + base);
    }

    float sdot[SPT], ndot[SPT];
#pragma unroll
    for (int e = 0; e < SPT; ++e) { sdot[e] = 0.f; ndot[e] = 0.f; }

#pragma unroll
    for (int hh = 0; hh < HH; ++hh) {
        const int   h  = (hh + rot) & 7;
        const float a  = amp[h];
        const float ph = phi[h] * INV2PIf;
        const float kf = (float)(h + 1);

        ndot[0] = fmaf(a, m[hh].x, ndot[0]);
        ndot[1] = fmaf(a, m[hh].y, ndot[1]);
        ndot[2] = fmaf(a, m[hh].z, ndot[2]);
        ndot[3] = fmaf(a, m[hh].w, ndot[3]);

#pragma unroll
        for (int e = 0; e < SPT; ++e) {
            const float r  = fmaf(kf, cs[e], ph);   // k*cs + phi
            const float fx = r - rintf(r);          // reduce to [-0.5, 0.5] rev
            sdot[e] = fmaf(a, sin_rev(fx), sdot[e]);
        }
    }

    const float a8 = amp[HH];
    const float UV = (float)(0.1 / (3.0 * 0.003));  // ALPHA / (3*SIGMA)

    float tmp[SPT];
#pragma unroll
    for (int e = 0; e < SPT; ++e) {
        const float x = voiced ? fmaf(ALPHA, sdot[e], ndot[e]) : UV * ndot[e];
        tmp[e] = tanh_fast(x + a8);
    }

    *reinterpret_cast<float4*>(out + base) =
        make_float4(tmp[0], tmp[1], tmp[2], tmp[3]);
}

// ---------------------------------------------------------------------------
extern "C" void kernel_launch(void* const* d_in, const int* in_sizes, int n_in,
                              void* d_out, int out_size, void* d_ws, size_t ws_size,
                              hipStream_t stream) {
    const float* f0s   = (const float*)d_in[0];   // [32, 500]
    const float* phi   = (const float*)d_in[1];   // [8]
    const float* amp   = (const float*)d_in[2];   // [9]
    const float* noise = (const float*)d_in[3];   // [8, 32, 120000]
    float* out = (float*)d_out;                   // [32, 120000]

    const int nblocks = (BB * TT) / (BLK * SPT);  // 3750, exact
    synth_fused<<<nblocks, BLK, 0, stream>>>(f0s, phi, amp, noise, out);
}

// Round 9
// 27.609 us; speedup vs baseline: 1.0323x; 1.0323x over previous
//
#include <hip/hip_runtime.h>
#include <math.h>

// Problem constants (match reference)
constexpr int   BB    = 32;
constexpr int   NF    = 500;
constexpr int   FS    = 240;
constexpr int   TT    = NF * FS;     // 120000 samples per row
constexpr int   HH    = 8;
constexpr float ALPHA = 0.1f;

constexpr int BLK     = 256;
constexpr int CPR     = 24;              // chunks per row
constexpr int CH_SAMP = TT / CPR;        // 5000 samples per chunk (mult of 4)
constexpr int CH_QUAD = CH_SAMP / 4;     // 1250 float4-quads per chunk
constexpr int NIT     = (CH_QUAD + BLK - 1) / BLK;   // 5 iterations
// grid = 32 rows * 24 chunks = 768 blocks = 3 per CU; a block never crosses rows.

__device__ __forceinline__ float sin_rev(float fr) {
#if __has_builtin(__builtin_amdgcn_sinf)
    return __builtin_amdgcn_sinf(fr);        // v_sin_f32: D = sin(S0 * 2pi)
#else
    return __sinf(fr * 6.28318530717958647692f);
#endif
}

__device__ __forceinline__ float tanh_fast(float x) {
    // tanh(x) = 1 - 2/(e^{2x}+1); exp saturation gives correct +-1 limits.
    const float e = __expf(2.0f * x);
#if __has_builtin(__builtin_amdgcn_rcpf)
    const float r = __builtin_amdgcn_rcpf(e + 1.0f);
#else
    const float r = 1.0f / (e + 1.0f);
#endif
    return fmaf(-2.0f, r, 1.0f);
}

__global__ __launch_bounds__(BLK) void synth_fused(const float* __restrict__ f0s,
                                                   const float* __restrict__ phi,
                                                   const float* __restrict__ amp,
                                                   const float* __restrict__ noise,
                                                   float* __restrict__ out) {
    const int bid  = blockIdx.x;
    const int tid  = threadIdx.x;
    const int lane = tid & 63;
    const int wv   = tid >> 6;

    const int b = bid / CPR;            // row
    const int c = bid % CPR;            // chunk within row

    __shared__ float2 sfr[NF];          // {frac(prefix_rev) at frame start, dphi_rev}
    __shared__ double wtot[BLK / 64];

    const float  TWO_PI_F = 6.28318530717958647692f;
    const double INV_2PI  = 0.15915494309189533576;

    // ---- cooperative frame-level phase prefix scan (once per block) ----
    {
        const int fi = 2 * tid;
        double d0 = 0.0, d1 = 0.0;
        if (fi < NF) {
            const float dphi = (TWO_PI_F * f0s[b * NF + fi]) / 24000.0f;  // f32, np op order
            d0 = (double)dphi * INV_2PI;
        }
        if (fi + 1 < NF) {
            const float dphi = (TWO_PI_F * f0s[b * NF + fi + 1]) / 24000.0f;
            d1 = (double)dphi * INV_2PI;
        }

        const double s = (d0 + d1) * 240.0;
        double run = s;
        for (int delta = 1; delta < 64; delta <<= 1) {
            const double o = __shfl_up(run, delta, 64);
            if (lane >= delta) run += o;
        }
        if (lane == 63) wtot[wv] = run;
        __syncthreads();

        double woff = 0.0;
        for (int w2 = 0; w2 < wv; ++w2) woff += wtot[w2];
        double pref = woff + (run - s);

        if (fi < NF) {
            const double fx0 = pref - rint(pref);
            sfr[fi] = make_float2((float)fx0, (float)d0);
            if (fi + 1 < NF) {
                const double p1  = pref + d0 * 240.0;
                const double fx1 = p1 - rint(p1);
                sfr[fi + 1] = make_float2((float)fx1, (float)d1);
            }
        }
        __syncthreads();
    }

    // ---- per-wave rotated harmonic tables ----
    const float INV2PIf = 0.15915494309189533576f;
    const int   rot     = (bid * 4 + wv) & 7;
    const size_t HSTR   = (size_t)BB * (size_t)TT;

    float a_r[HH], ph_r[HH], kf_r[HH];
#pragma unroll
    for (int hh = 0; hh < HH; ++hh) {
        const int h = (hh + rot) & 7;
        a_r[hh]  = amp[h];
        ph_r[hh] = phi[h] * INV2PIf;
        kf_r[hh] = (float)(h + 1);
    }
    const float a8 = amp[HH];
    const float UV = (float)(0.1 / (3.0 * 0.003));   // ALPHA / (3*SIGMA)

    const size_t rowbase = (size_t)b * TT + (size_t)c * CH_SAMP;

#define LOAD_M(M, IT)                                                          \
    {                                                                          \
        const int q = min((IT) * BLK + tid, CH_QUAD - 1);                      \
        const size_t off = rowbase + (size_t)q * 4;                            \
        _Pragma("unroll")                                                      \
        for (int hh = 0; hh < HH; ++hh) {                                      \
            const int h = (hh + rot) & 7;                                      \
            M[hh] = *reinterpret_cast<const float4*>(noise + (size_t)h * HSTR + off); \
        }                                                                      \
    }

#define BODY_M(M, IT)                                                          \
    {                                                                          \
        const int  qr  = (IT) * BLK + tid;                                     \
        const bool act = (qr < CH_QUAD);                                       \
        const int  q   = act ? qr : (CH_QUAD - 1);                             \
        const int  t_loc = q * 4;                                              \
        const int  t  = c * CH_SAMP + t_loc;                                   \
        const int  f  = t / FS;                                                \
        const int  j  = t - f * FS;                                            \
        const float2 fd = sfr[f];                                              \
        const float  dr = fd.y;                                                \
        const bool   voiced = (dr > 0.0f);                                     \
        float cs[4];                                                           \
        cs[0] = fd.x + (float)(j + 1) * dr;                                    \
        cs[1] = cs[0] + dr;  cs[2] = cs[1] + dr;  cs[3] = cs[2] + dr;          \
        float sdot[4] = {0.f, 0.f, 0.f, 0.f};                                  \
        float ndot[4] = {0.f, 0.f, 0.f, 0.f};                                  \
        _Pragma("unroll")                                                      \
        for (int hh = 0; hh < HH; ++hh) {                                      \
            const float a  = a_r[hh];                                          \
            const float ph = ph_r[hh];                                         \
            const float kf = kf_r[hh];                                         \
            ndot[0] = fmaf(a, M[hh].x, ndot[0]);                               \
            ndot[1] = fmaf(a, M[hh].y, ndot[1]);                               \
            ndot[2] = fmaf(a, M[hh].z, ndot[2]);                               \
            ndot[3] = fmaf(a, M[hh].w, ndot[3]);                               \
            _Pragma("unroll")                                                  \
            for (int e = 0; e < 4; ++e) {                                      \
                const float r  = fmaf(kf, cs[e], ph);                          \
                const float fx = r - rintf(r);                                 \
                sdot[e] = fmaf(a, sin_rev(fx), sdot[e]);                       \
            }                                                                  \
        }                                                                      \
        float tmp[4];                                                          \
        _Pragma("unroll")                                                      \
        for (int e = 0; e < 4; ++e) {                                          \
            const float x = voiced ? fmaf(ALPHA, sdot[e], ndot[e]) : UV * ndot[e]; \
            tmp[e] = tanh_fast(x + a8);                                        \
        }                                                                      \
        if (act) {                                                             \
            *reinterpret_cast<float4*>(out + (size_t)b * TT + t) =             \
                make_float4(tmp[0], tmp[1], tmp[2], tmp[3]);                   \
        }                                                                      \
    }

    // ---- 1-deep software pipeline over NIT=5 iterations (static reg sets) ----
    float4 mA[HH], mB[HH];
    LOAD_M(mA, 0)
    LOAD_M(mB, 1)  BODY_M(mA, 0)
    LOAD_M(mA, 2)  BODY_M(mB, 1)
    LOAD_M(mB, 3)  BODY_M(mA, 2)
    LOAD_M(mA, 4)  BODY_M(mB, 3)
    BODY_M(mA, 4)

#undef LOAD_M
#undef BODY_M
}

// ---------------------------------------------------------------------------
extern "C" void kernel_launch(void* const* d_in, const int* in_sizes, int n_in,
                              void* d_out, int out_size, void* d_ws, size_t ws_size,
                              hipStream_t stream) {
    const float* f0s   = (const float*)d_in[0];   // [32, 500]
    const float* phi   = (const float*)d_in[1];   // [8]
    const float* amp   = (const float*)d_in[2];   // [9]
    const float* noise = (const float*)d_in[3];   // [8, 32, 120000]
    float* out = (float*)d_out;                   // [32, 120000]

    const int nblocks = BB * CPR;                 // 768
    synth_fused<<<nblocks, BLK, 0, stream>>>(f0s, phi, amp, noise, out);
}

// Round 10
// 27.525 us; speedup vs baseline: 1.0355x; 1.0031x over previous
//
#include <hip/hip_runtime.h>
#include <math.h>

// Problem constants (match reference)
constexpr int   BB    = 32;
constexpr int   NF    = 500;
constexpr int   FS    = 240;
constexpr int   TT    = NF * FS;     // 120000 samples per row
constexpr int   HH    = 8;
constexpr float ALPHA = 0.1f;

constexpr int BLK     = 256;
constexpr int CPR     = 24;              // chunks per row
constexpr int CH_SAMP = TT / CPR;        // 5000 samples per chunk (mult of 4)
constexpr int CH_QUAD = CH_SAMP / 4;     // 1250 float4-quads per chunk
// grid = 32 rows * 24 chunks = 768 blocks = 3 per CU; a block never crosses rows.

typedef float f32x4 __attribute__((ext_vector_type(4)));   // for nontemporal store

__device__ __forceinline__ float sin_rev(float fr) {
#if __has_builtin(__builtin_amdgcn_sinf)
    return __builtin_amdgcn_sinf(fr);        // v_sin_f32: D = sin(S0 * 2pi)
#else
    return __sinf(fr * 6.28318530717958647692f);
#endif
}

__device__ __forceinline__ float tanh_fast(float x) {
    // tanh(x) = 1 - 2/(e^{2x}+1); exp saturation gives correct +-1 limits.
    const float e = __expf(2.0f * x);
#if __has_builtin(__builtin_amdgcn_rcpf)
    const float r = __builtin_amdgcn_rcpf(e + 1.0f);
#else
    const float r = 1.0f / (e + 1.0f);
#endif
    return fmaf(-2.0f, r, 1.0f);
}

__global__ __launch_bounds__(BLK) void synth_fused(const float* __restrict__ f0s,
                                                   const float* __restrict__ phi,
                                                   const float* __restrict__ amp,
                                                   const float* __restrict__ noise,
                                                   float* __restrict__ out) {
    const int bid  = blockIdx.x;
    const int tid  = threadIdx.x;
    const int lane = tid & 63;
    const int wv   = tid >> 6;

    const int b = bid / CPR;            // row
    const int c = bid % CPR;            // chunk within row

    __shared__ float2 sfr[NF];          // {frac(prefix_rev) at frame start, dphi_rev}
    __shared__ double wtot[BLK / 64];

    const float  TWO_PI_F = 6.28318530717958647692f;
    const double INV_2PI  = 0.15915494309189533576;

    // ---- cooperative frame-level phase prefix scan (once per block) ----
    {
        const int fi = 2 * tid;
        double d0 = 0.0, d1 = 0.0;
        if (fi < NF) {
            const float dphi = (TWO_PI_F * f0s[b * NF + fi]) / 24000.0f;  // f32, np op order
            d0 = (double)dphi * INV_2PI;
        }
        if (fi + 1 < NF) {
            const float dphi = (TWO_PI_F * f0s[b * NF + fi + 1]) / 24000.0f;
            d1 = (double)dphi * INV_2PI;
        }

        const double s = (d0 + d1) * 240.0;
        double run = s;
        for (int delta = 1; delta < 64; delta <<= 1) {
            const double o = __shfl_up(run, delta, 64);
            if (lane >= delta) run += o;
        }
        if (lane == 63) wtot[wv] = run;
        __syncthreads();

        double woff = 0.0;
        for (int w2 = 0; w2 < wv; ++w2) woff += wtot[w2];
        double pref = woff + (run - s);

        if (fi < NF) {
            const double fx0 = pref - rint(pref);
            sfr[fi] = make_float2((float)fx0, (float)d0);
            if (fi + 1 < NF) {
                const double p1  = pref + d0 * 240.0;
                const double fx1 = p1 - rint(p1);
                sfr[fi + 1] = make_float2((float)fx1, (float)d1);
            }
        }
        __syncthreads();
    }

    // ---- per-wave rotated harmonic tables ----
    const float INV2PIf = 0.15915494309189533576f;
    const int   rot     = (bid * 4 + wv) & 7;
    const size_t HSTR   = (size_t)BB * (size_t)TT;

    float a_r[HH], ph_r[HH], kf_r[HH];
#pragma unroll
    for (int hh = 0; hh < HH; ++hh) {
        const int h = (hh + rot) & 7;
        a_r[hh]  = amp[h];
        ph_r[hh] = phi[h] * INV2PIf;
        kf_r[hh] = (float)(h + 1);
    }
    const float a8 = amp[HH];
    const float UV = (float)(0.1 / (3.0 * 0.003));   // ALPHA / (3*SIGMA)

    const size_t rowbase = (size_t)b * TT + (size_t)c * CH_SAMP;

#define LOAD_M(M, IT)                                                          \
    {                                                                          \
        const int q = min((IT) * BLK + tid, CH_QUAD - 1);                      \
        const size_t off = rowbase + (size_t)q * 4;                            \
        _Pragma("unroll")                                                      \
        for (int hh = 0; hh < HH; ++hh) {                                      \
            const int h = (hh + rot) & 7;                                      \
            M[hh] = *reinterpret_cast<const float4*>(noise + (size_t)h * HSTR + off); \
        }                                                                      \
    }

#define BODY_M(M, IT)                                                          \
    {                                                                          \
        const int  qr  = (IT) * BLK + tid;                                     \
        const bool act = (qr < CH_QUAD);                                       \
        const int  q   = act ? qr : (CH_QUAD - 1);                             \
        const int  t_loc = q * 4;                                              \
        const int  t  = c * CH_SAMP + t_loc;                                   \
        const int  f  = t / FS;                                                \
        const int  j  = t - f * FS;                                            \
        const float2 fd = sfr[f];                                              \
        const float  dr = fd.y;                                                \
        const bool   voiced = (dr > 0.0f);                                     \
        float cs[4];                                                           \
        cs[0] = fd.x + (float)(j + 1) * dr;                                    \
        cs[1] = cs[0] + dr;  cs[2] = cs[1] + dr;  cs[3] = cs[2] + dr;          \
        float sdot[4] = {0.f, 0.f, 0.f, 0.f};                                  \
        float ndot[4] = {0.f, 0.f, 0.f, 0.f};                                  \
        _Pragma("unroll")                                                      \
        for (int hh = 0; hh < HH; ++hh) {                                      \
            const float a  = a_r[hh];                                          \
            const float ph = ph_r[hh];                                         \
            const float kf = kf_r[hh];                                         \
            ndot[0] = fmaf(a, M[hh].x, ndot[0]);                               \
            ndot[1] = fmaf(a, M[hh].y, ndot[1]);                               \
            ndot[2] = fmaf(a, M[hh].z, ndot[2]);                               \
            ndot[3] = fmaf(a, M[hh].w, ndot[3]);                               \
            _Pragma("unroll")                                                  \
            for (int e = 0; e < 4; ++e) {                                      \
                const float r  = fmaf(kf, cs[e], ph);                          \
                const float fx = r - rintf(r);                                 \
                sdot[e] = fmaf(a, sin_rev(fx), sdot[e]);                       \
            }                                                                  \
        }                                                                      \
        float tmp[4];                                                          \
        _Pragma("unroll")                                                      \
        for (int e = 0; e < 4; ++e) {                                          \
            const float x = voiced ? fmaf(ALPHA, sdot[e], ndot[e]) : UV * ndot[e]; \
            tmp[e] = tanh_fast(x + a8);                                        \
        }                                                                      \
        if (act) {                                                             \
            f32x4 ov; ov.x = tmp[0]; ov.y = tmp[1]; ov.z = tmp[2]; ov.w = tmp[3]; \
            __builtin_nontemporal_store(ov,                                    \
                reinterpret_cast<f32x4*>(out + (size_t)b * TT + t));           \
        }                                                                      \
    }

    // ---- 1-deep software pipeline over 5 iterations (static reg sets) ----
    float4 mA[HH], mB[HH];
    LOAD_M(mA, 0)
    LOAD_M(mB, 1)  BODY_M(mA, 0)
    LOAD_M(mA, 2)  BODY_M(mB, 1)
    LOAD_M(mB, 3)  BODY_M(mA, 2)
    LOAD_M(mA, 4)  BODY_M(mB, 3)
    BODY_M(mA, 4)

#undef LOAD_M
#undef BODY_M
}

// ---------------------------------------------------------------------------
extern "C" void kernel_launch(void* const* d_in, const int* in_sizes, int n_in,
                              void* d_out, int out_size, void* d_ws, size_t ws_size,
                              hipStream_t stream) {
    const float* f0s   = (const float*)d_in[0];   // [32, 500]
    const float* phi   = (const float*)d_in[1];   // [8]
    const float* amp   = (const float*)d_in[2];   // [9]
    const float* noise = (const float*)d_in[3];   // [8, 32, 120000]
    float* out = (float*)d_out;                   // [32, 120000]

    const int nblocks = BB * CPR;                 // 768
    synth_fused<<<nblocks, BLK, 0, stream>>>(f0s, phi, amp, noise, out);
}